// Round 13
// baseline (933.234 us; speedup 1.0000x reference)
//
#include <hip/hip_runtime.h>
#include <hip/hip_bf16.h>

typedef __attribute__((ext_vector_type(8))) __bf16 bf16x8;
typedef __attribute__((ext_vector_type(4))) float f32x4;

#define MFMA(a,b,c) __builtin_amdgcn_mfma_f32_16x16x32_bf16((a),(b),(c),0,0,0)

__device__ __forceinline__ bf16x8 cvt8(float4 a, float4 b){
  bf16x8 r;
  r[0]=(__bf16)a.x; r[1]=(__bf16)a.y; r[2]=(__bf16)a.z; r[3]=(__bf16)a.w;
  r[4]=(__bf16)b.x; r[5]=(__bf16)b.y; r[6]=(__bf16)b.z; r[7]=(__bf16)b.w;
  return r;
}

// ---- fused setup: blocks 0-15 pack weights (Wp 2560 + Wq 1536 frags),
// blocks 16+ zero the counter/stat region.
__global__ void setup_k(const float* __restrict__ W_sg, const float* __restrict__ W_dg,
                        const float* __restrict__ W_eg, const float* __restrict__ W_su,
                        const float* __restrict__ W_du,
                        bf16x8* __restrict__ Wp, bf16x8* __restrict__ Wq,
                        int4* __restrict__ zp, int nz4){
  if (blockIdx.x < 16){
    int tid = blockIdx.x*256 + threadIdx.x;
    if (tid >= 2560 + 1536) return;
    int lane = tid & 63, g = lane>>4, c = lane&15;
    if (tid < 2560){
      int frag = (tid>>6)&7, m = tid>>9;
      const float* Ws[5] = {W_sg, W_dg, W_eg, W_su, W_du};
      const float* W = Ws[m];
      int kt = frag>>2, nt = frag&3;
      bf16x8 v;
      #pragma unroll
      for (int j=0;j<8;j++) v[j] = (__bf16)W[(kt*32+g*8+j)*64 + nt*16 + c];
      Wp[tid] = v;
    } else {
      int t2 = tid - 2560;
      int frag = (t2>>6)&7, m = t2>>9;   // 0..2
      const float* Ws[3] = {W_eg, W_sg, W_dg};
      const float* W = Ws[m];
      int mt = frag>>1, kh = frag&1;
      bf16x8 v;
      #pragma unroll
      for (int j=0;j<8;j++) v[j] = (__bf16)W[(kh*32+g*8+j)*64 + mt*16 + c];
      Wq[t2] = v;
    }
  } else {
    int i = (blockIdx.x-16)*256 + threadIdx.x, st = (gridDim.x-16)*256;
    for (; i<nz4; i+=st) zp[i] = make_int4(0,0,0,0);
  }
}

// ---- fused: blocks [0,nxf) node transforms; blocks [nxf,+) dst histogram.
__global__ __launch_bounds__(256) void xform_hist_k(
    const float* __restrict__ nf, const bf16x8* __restrict__ Wp,
    const float* __restrict__ b_su, const float* __restrict__ b_du,
    float* __restrict__ A_src, float* __restrict__ Bh, int ntiles, int nxf,
    const int* __restrict__ dst, int* __restrict__ cnt, int E)
{
  if ((int)blockIdx.x < nxf){
    int lane = threadIdx.x & 63;
    int gw = blockIdx.x*4 + (threadIdx.x>>6);
    if (gw >= ntiles) return;
    int g = lane>>4, c = lane&15;
    long base = (long)gw*16;
    const float* rp = nf + (base + c)*64 + g*8;
    float4 a0 = *(const float4*)rp,      a1 = *(const float4*)(rp+4);
    float4 a2 = *(const float4*)(rp+32), a3 = *(const float4*)(rp+36);
    bf16x8 A0 = cvt8(a0,a1), A1 = cvt8(a2,a3);
    const float* biases[2] = {b_su,b_du};
    float* outs[2] = {A_src,Bh};
    const int mats[2] = {3,4};
    #pragma unroll
    for (int i=0;i<2;i++){
      #pragma unroll
      for (int nt=0;nt<4;nt++){
        f32x4 acc = {0.f,0.f,0.f,0.f};
        acc = MFMA(A0, Wp[(mats[i]*8+nt)*64+lane],   acc);
        acc = MFMA(A1, Wp[(mats[i]*8+4+nt)*64+lane], acc);
        int col = c + nt*16;
        float bb = biases[i][col];
        #pragma unroll
        for (int e=0;e<4;e++) outs[i][(base+4*g+e)*64 + col] = acc[e] + bb;
      }
    }
  } else {
    int nb = gridDim.x - nxf;
    int i = (blockIdx.x-nxf)*256 + threadIdx.x, st = nb*256;
    for (; i<E; i+=st) atomicAdd(&cnt[dst[i]], 1);
  }
}

__global__ __launch_bounds__(1024) void scan_k(const int* __restrict__ cnt,
                                               int* __restrict__ row, int Nn){
  __shared__ int part[1024];
  int t = threadIdx.x;
  int C = (Nn + 1023) >> 10;
  int lo = t*C;
  int hi = lo + C; if (hi > Nn) hi = Nn;
  int s = 0;
  for (int i=lo; i<hi; i++) s += cnt[i];
  part[t] = s;
  __syncthreads();
  for (int off=1; off<1024; off<<=1){
    int v = part[t];
    int u = (t>=off) ? part[t-off] : 0;
    __syncthreads();
    part[t] = v + u;
    __syncthreads();
  }
  int excl = (t==0) ? 0 : part[t-1];
  for (int i=lo; i<hi; i++){ row[i] = excl; excl += cnt[i]; }
  if (t==1023) row[Nn] = excl;
}

struct TileF {
  float4 e0,e1,e2,e3,s0,s1,s2,s3,d0,d1,d2,d3;
};

__device__ __forceinline__ TileF ld_tile(const float* __restrict__ ef,
                                         const float* __restrict__ nf,
                                         long base, int c, int g, int sc, int dc){
  TileF t;
  const float* rpe = ef + (base+c)*64 + g*8;
  const float* rps = nf + (long)sc*64 + g*8;
  const float* rpd = nf + (long)dc*64 + g*8;
  t.e0=*(const float4*)rpe;      t.e1=*(const float4*)(rpe+4);
  t.e2=*(const float4*)(rpe+32); t.e3=*(const float4*)(rpe+36);
  t.s0=*(const float4*)rps;      t.s1=*(const float4*)(rps+4);
  t.s2=*(const float4*)(rps+32); t.s3=*(const float4*)(rps+36);
  t.d0=*(const float4*)rpd;      t.d1=*(const float4*)(rpd+4);
  t.d2=*(const float4*)(rpd+32); t.d3=*(const float4*)(rpd+36);
  return t;
}

// ---- fused: blocks [0,NFILL) CSR fill; blocks [NFILL,+) phaseA with a
// 2-deep register pipeline: tile t+1's 12 loads are issued before tile t's
// MFMA+store, indices prefetched 2 ahead.
#define NFILL 1024
__global__ __launch_bounds__(256) void fillA_k(
    const int* __restrict__ src, const int* __restrict__ dst,
    const int* __restrict__ rowp, int* __restrict__ cnt2,
    int2* __restrict__ pairs, int E,
    const float* __restrict__ ef, const float* __restrict__ nf,
    const float* __restrict__ b_sg, const float* __restrict__ b_dg,
    const float* __restrict__ b_eg,
    const bf16x8* __restrict__ Wq,
    __bf16* __restrict__ m16, int ntiles)
{
  __shared__ bf16x8 wl[24*64];
  if (blockIdx.x < NFILL){
    int i = blockIdx.x*256 + threadIdx.x, st = NFILL*256;
    for (; i<E; i+=st){
      int d = dst[i];
      int pos = rowp[d] + atomicAdd(&cnt2[d], 1);
      pairs[pos] = make_int2(i, src[i]);
    }
    return;
  }
  {
    int t = threadIdx.x;
    #pragma unroll
    for (int i=0;i<6;i++) wl[i*256+t] = Wq[i*256+t];
  }
  __syncthreads();
  int lane = threadIdx.x & 63, g = lane>>4, c = lane&15;
  int gw = (blockIdx.x-NFILL)*4 + (threadIdx.x>>6);
  int nw = (gridDim.x-NFILL)*4;
  float bias2[4][4];
  #pragma unroll
  for (int mt=0;mt<4;mt++)
    #pragma unroll
    for (int e=0;e<4;e++){
      int f = mt*16 + 4*g + e;
      bias2[mt][e] = b_sg[f] + b_dg[f] + b_eg[f];
    }
  if (gw >= ntiles) return;
  // prologue: indices for gw, data for gw, indices for gw+nw
  int sc = src[(long)gw*16 + c], dc = dst[(long)gw*16 + c];
  TileF cur = ld_tile(ef, nf, (long)gw*16, c, g, sc, dc);
  int t1i = gw + nw;
  int sn = sc, dn = dc;
  if (t1i < ntiles){ sn = src[(long)t1i*16 + c]; dn = dst[(long)t1i*16 + c]; }
  for (int tt=gw; tt<ntiles; tt+=nw){
    int t1 = tt + nw;
    // issue next tile's 12 data loads (overlap with this tile's compute)
    TileF nxt;
    if (t1 < ntiles) nxt = ld_tile(ef, nf, (long)t1*16, c, g, sn, dn);
    // prefetch indices 2 ahead
    int t2 = t1 + nw;
    if (t2 < ntiles){ sn = src[(long)t2*16 + c]; dn = dst[(long)t2*16 + c]; }
    // compute current tile
    bf16x8 BE0=cvt8(cur.e0,cur.e1), BE1=cvt8(cur.e2,cur.e3);
    bf16x8 BS0=cvt8(cur.s0,cur.s1), BS1=cvt8(cur.s2,cur.s3);
    bf16x8 BD0=cvt8(cur.d0,cur.d1), BD1=cvt8(cur.d2,cur.d3);
    long base = (long)tt*16;
    #pragma unroll
    for (int mt=0;mt<4;mt++){
      f32x4 am = {0.f,0.f,0.f,0.f};
      am = MFMA(wl[((0*4+mt)*2+0)*64+lane], BE0, am);
      am = MFMA(wl[((0*4+mt)*2+1)*64+lane], BE1, am);
      am = MFMA(wl[((1*4+mt)*2+0)*64+lane], BS0, am);
      am = MFMA(wl[((1*4+mt)*2+1)*64+lane], BS1, am);
      am = MFMA(wl[((2*4+mt)*2+0)*64+lane], BD0, am);
      am = MFMA(wl[((2*4+mt)*2+1)*64+lane], BD1, am);
      union { __bf16 h[4]; uint2 u; } pk;
      #pragma unroll
      for (int e=0;e<4;e++) pk.h[e] = (__bf16)(am[e] + bias2[mt][e]);
      *(uint2*)(m16 + (base+c)*64 + mt*16 + 4*g) = pk.u;
    }
    cur = nxt;
  }
}

// ---- phaseB: node-major over CSR rows; 8-edge groups with pair-prefetch.
__global__ __launch_bounds__(256) void phaseB(
    const __bf16* __restrict__ m16, const int2* __restrict__ pairs,
    const float* __restrict__ Bh, const int* __restrict__ rowp,
    float* __restrict__ A_src,
    float* __restrict__ est, float* __restrict__ nst, int Nn)
{
  __shared__ float sst[256];
  sst[threadIdx.x] = 0.f;
  __syncthreads();
  int lane = threadIdx.x & 63, w = threadIdx.x>>6;
  int chunk = (Nn + gridDim.x - 1)/gridDim.x;
  int n0 = blockIdx.x*chunk;
  int n1 = n0 + chunk; if (n1 > Nn) n1 = Nn;
  float e1=0.f, e2=0.f, p1=0.f, p2=0.f;
  for (int n=n0+w; n<n1; n+=4){
    int r0 = rowp[n], r1 = rowp[n+1];
    float ssum=0.f, bsum=0.f;
    int r = r0;
    int2 q[8];
    bool have = (r + 8 <= r1);
    if (have){
      #pragma unroll
      for (int j=0;j<8;j++) q[j] = pairs[r+j];
    }
    while (have){
      int rn = r + 8;
      bool haven = (rn + 8 <= r1);
      int2 qn[8];
      if (haven){
        #pragma unroll
        for (int j=0;j<8;j++) qn[j] = pairs[rn+j];
      }
      float mv[8], bh[8];
      #pragma unroll
      for (int j=0;j<8;j++) mv[j] = (float)m16[(long)q[j].x*64 + lane];
      #pragma unroll
      for (int j=0;j<8;j++) bh[j] = Bh[(long)q[j].y*64 + lane];
      #pragma unroll
      for (int j=0;j<8;j++){
        float sg = 1.f/(1.f+__expf(-mv[j]));
        ssum += sg; bsum += bh[j]*sg;
        e1 += mv[j]; e2 += mv[j]*mv[j];
      }
      if (haven){
        #pragma unroll
        for (int j=0;j<8;j++) q[j] = qn[j];
      }
      r = rn; have = haven;
    }
    for (; r < r1; ++r){
      int2 q0 = pairs[r];
      float mv0 = (float)m16[(long)q0.x*64 + lane];
      float bh0 = Bh[(long)q0.y*64 + lane];
      float sg0 = 1.f/(1.f+__expf(-mv0));
      ssum += sg0; bsum += bh0*sg0;
      e1 += mv0;   e2 += mv0*mv0;
    }
    long xi = (long)n*64 + lane;
    float xp = A_src[xi] + bsum/(ssum+1e-6f);
    A_src[xi] = xp;
    p1 += xp; p2 += xp*xp;
  }
  atomicAdd(&sst[lane],     e1);
  atomicAdd(&sst[64+lane],  e2);
  atomicAdd(&sst[128+lane], p1);
  atomicAdd(&sst[192+lane], p2);
  __syncthreads();
  int t = threadIdx.x;
  if (t < 128) atomicAdd(&est[t], sst[t]);
  else         atomicAdd(&nst[t-128], sst[t]);
}

// ---- fused finals: blocks [0,NNF) x-output; blocks [NNF,+) y-output.
#define NNF 1024
__global__ __launch_bounds__(256) void finals_k(
    const float* __restrict__ nf, const float* __restrict__ xpre,
    const float* __restrict__ nst, const float* __restrict__ gn,
    const float* __restrict__ btn, float* __restrict__ xo, int Nn,
    const __bf16* __restrict__ m16, const float* __restrict__ ef,
    const float* __restrict__ est, const float* __restrict__ ge,
    const float* __restrict__ bte, float* __restrict__ y, float invE, long E)
{
  if (blockIdx.x < NNF){
    long tid = (long)blockIdx.x*256 + threadIdx.x;
    long stride = (long)NNF*256;
    int col = (int)(tid & 63);
    float invN = 1.f/(float)Nn;
    float mu = nst[col]*invN;
    float var = nst[64+col]*invN - mu*mu;
    float rs = rsqrtf(var + 1e-5f);
    float aa = gn[col]*rs;
    float bb = btn[col] - mu*aa;
    long total = (long)Nn*64;
    for (long i=tid; i<total; i+=stride){
      float z = xpre[i]*aa + bb;
      xo[i] = nf[i] + z/(1.f+__expf(-z));
    }
  } else {
    int oct = threadIdx.x & 7;
    float aa[8], bb[8];
    #pragma unroll
    for (int j=0;j<8;j++){
      int col = oct*8 + j;
      float mu = est[col]*invE;
      float var = est[64+col]*invE - mu*mu;
      float rs = rsqrtf(var + 1e-5f);
      float ga = ge[col]*rs;
      aa[j] = ga; bb[j] = bte[col] - mu*ga;
    }
    long tid = (long)(blockIdx.x-NNF)*256 + threadIdx.x;
    long pstep = ((long)(gridDim.x-NNF)*256) >> 3;
    for (long p = tid>>3; p < E; p += pstep){
      bf16x8 mv = *(const bf16x8*)&m16[p*64 + oct*8];
      const float* rp = ef + p*64 + oct*8;
      float4 f0 = *(const float4*)rp, f1 = *(const float4*)(rp+4);
      float o[8];
      #pragma unroll
      for (int j=0;j<8;j++){
        float z = aa[j]*(float)mv[j] + bb[j];
        float ev = (j<4) ? ((const float*)&f0)[j] : ((const float*)&f1)[j-4];
        o[j] = ev + z/(1.f+__expf(-z));
      }
      float* yp = y + p*64 + oct*8;
      *(float4*)yp     = make_float4(o[0],o[1],o[2],o[3]);
      *(float4*)(yp+4) = make_float4(o[4],o[5],o[6],o[7]);
    }
  }
}

extern "C" void kernel_launch(void* const* d_in, const int* in_sizes, int n_in,
                              void* d_out, int out_size, void* d_ws, size_t ws_size,
                              hipStream_t stream){
  const float* nf  = (const float*)d_in[0];
  const float* ef  = (const float*)d_in[1];
  const int*   src = (const int*)d_in[2];
  const int*   dst = (const int*)d_in[3];
  const float* W_sg=(const float*)d_in[4];  const float* b_sg=(const float*)d_in[5];
  const float* W_dg=(const float*)d_in[6];  const float* b_dg=(const float*)d_in[7];
  const float* W_eg=(const float*)d_in[8];  const float* b_eg=(const float*)d_in[9];
  const float* W_su=(const float*)d_in[10]; const float* b_su=(const float*)d_in[11];
  const float* W_du=(const float*)d_in[12]; const float* b_du=(const float*)d_in[13];
  const float* gn=(const float*)d_in[14];   const float* btn=(const float*)d_in[15];
  const float* ge=(const float*)d_in[16];   const float* bte=(const float*)d_in[17];

  int Nn = in_sizes[0]/64;
  int Ee = in_sizes[2];
  size_t Nf = (size_t)Nn*64;
  size_t Es = (size_t)Ee;

  float* ws    = (float*)d_ws;
  float* A_src = ws;                          // Nf (becomes x_pre)
  float* Bh    = ws + Nf;                     // Nf
  __bf16* m16  = (__bf16*)(ws + 2*Nf);        // 32*Es floats
  int2*  pairs = (int2*)(ws + 2*Nf + 32*Es);  // 2*Es floats
  int*   cnt   = (int*)(pairs + Es);          // Nn
  int*   cnt2  = cnt + Nn;                    // Nn
  float* est   = (float*)(cnt2 + Nn);         // 128
  float* nst   = est + 128;                   // 128
  int*   rowp  = (int*)(nst + 128);           // Nn+1
  size_t woff  = 2*Nf + 32*Es + 2*Es + 2*(size_t)Nn + 256 + (size_t)Nn + 1;
  woff = (woff + 15) & ~(size_t)15;
  bf16x8* Wp   = (bf16x8*)(ws + woff);        // 2560 frags
  bf16x8* Wq   = Wp + 2560;                   // 1536 frags

  float* xo = (float*)d_out;
  float* yo = xo + Nf;

  int nz4 = (int)((2*(size_t)Nn + 256) >> 2);
  setup_k<<<272,256,0,stream>>>(W_sg,W_dg,W_eg,W_su,W_du,Wp,Wq,(int4*)cnt,nz4);

  int ntn = Nn/16;
  int nxf = (ntn+3)/4;
  xform_hist_k<<<nxf+2048,256,0,stream>>>(nf,Wp,b_su,b_du,A_src,Bh,ntn,nxf,
                                          dst,cnt,Ee);
  scan_k<<<1,1024,0,stream>>>(cnt,rowp,Nn);
  int nte = Ee/16;
  fillA_k<<<NFILL+4096,256,0,stream>>>(src,dst,rowp,cnt2,pairs,Ee,
                                       ef,nf,b_sg,b_dg,b_eg,Wq,m16,nte);
  phaseB<<<4096,256,0,stream>>>(m16,pairs,Bh,rowp,A_src,est,nst,Nn);
  finals_k<<<NNF+4096,256,0,stream>>>(nf,A_src,nst,gn,btn,xo,Nn,
                                      m16,ef,est,ge,bte,yo,
                                      1.f/(float)Ee,(long)Ee);
}

// Round 14
// 902.456 us; speedup vs baseline: 1.0341x; 1.0341x over previous
//
#include <hip/hip_runtime.h>
#include <hip/hip_bf16.h>

typedef __attribute__((ext_vector_type(8))) __bf16 bf16x8;
typedef __attribute__((ext_vector_type(4))) float f32x4;

#define MFMA(a,b,c) __builtin_amdgcn_mfma_f32_16x16x32_bf16((a),(b),(c),0,0,0)

__device__ __forceinline__ bf16x8 cvt8(float4 a, float4 b){
  bf16x8 r;
  r[0]=(__bf16)a.x; r[1]=(__bf16)a.y; r[2]=(__bf16)a.z; r[3]=(__bf16)a.w;
  r[4]=(__bf16)b.x; r[5]=(__bf16)b.y; r[6]=(__bf16)b.z; r[7]=(__bf16)b.w;
  return r;
}

// ---- fused setup: blocks 0-15 pack weights into transposed A-operand layout,
// blocks 16+ zero the counter/stat region.
// Wq mats {0:eg,1:sg,2:dg,3:du,4:su}; frag=mt*2+kh; lane(c,g) holds
// W[kh*32+g*8+j][mt*16+c]  (A[m=c][k=g*8+j] of W^T slab) — 2560 frags.
__global__ void setup_k(const float* __restrict__ W_sg, const float* __restrict__ W_dg,
                        const float* __restrict__ W_eg, const float* __restrict__ W_su,
                        const float* __restrict__ W_du,
                        bf16x8* __restrict__ Wq,
                        int4* __restrict__ zp, int nz4){
  if (blockIdx.x < 16){
    int tid = blockIdx.x*256 + threadIdx.x;
    if (tid >= 2560) return;
    int lane = tid & 63, g = lane>>4, c = lane&15;
    int frag = (tid>>6)&7, m = tid>>9;
    const float* Ws[5] = {W_eg, W_sg, W_dg, W_du, W_su};
    const float* W = Ws[m];
    int mt = frag>>1, kh = frag&1;
    bf16x8 v;
    #pragma unroll
    for (int j=0;j<8;j++) v[j] = (__bf16)W[(kh*32+g*8+j)*64 + mt*16 + c];
    Wq[tid] = v;
  } else {
    int i = (blockIdx.x-16)*256 + threadIdx.x, st = (gridDim.x-16)*256;
    for (; i<nz4; i+=st) zp[i] = make_int4(0,0,0,0);
  }
}

// ---- fused: blocks [0,nxf): 4 node transforms via transposed MFMA ->
// e_src16/e_dst16/Bh16 (bf16 rows, NO bias) + A_src (f32, NO bias);
// blocks [nxf,+): dst histogram.
__global__ __launch_bounds__(256) void xform_hist_k(
    const float* __restrict__ nf, const bf16x8* __restrict__ Wq,
    __bf16* __restrict__ es16, __bf16* __restrict__ ed16,
    __bf16* __restrict__ bh16, float* __restrict__ A_src, int ntiles, int nxf,
    const int* __restrict__ dst, int* __restrict__ cnt, int E)
{
  if ((int)blockIdx.x < nxf){
    int lane = threadIdx.x & 63;
    int gw = blockIdx.x*4 + (threadIdx.x>>6);
    if (gw >= ntiles) return;
    int g = lane>>4, c = lane&15;
    long base = (long)gw*16;
    const float* rp = nf + (base + c)*64 + g*8;
    float4 a0 = *(const float4*)rp,      a1 = *(const float4*)(rp+4);
    float4 a2 = *(const float4*)(rp+32), a3 = *(const float4*)(rp+36);
    bf16x8 B0 = cvt8(a0,a1), B1 = cvt8(a2,a3);
    __bf16* outs[3] = {es16, ed16, bh16};
    const int mats[3] = {1,2,3};           // sg, dg, du
    #pragma unroll
    for (int i=0;i<3;i++){
      #pragma unroll
      for (int mt=0;mt<4;mt++){
        f32x4 am = {0.f,0.f,0.f,0.f};
        am = MFMA(Wq[(mats[i]*8+mt*2+0)*64+lane], B0, am);
        am = MFMA(Wq[(mats[i]*8+mt*2+1)*64+lane], B1, am);
        union { __bf16 h[4]; uint2 u; } pk;
        #pragma unroll
        for (int e=0;e<4;e++) pk.h[e] = (__bf16)am[e];
        *(uint2*)(outs[i] + (base+c)*64 + mt*16 + 4*g) = pk.u;
      }
    }
    #pragma unroll
    for (int mt=0;mt<4;mt++){
      f32x4 am = {0.f,0.f,0.f,0.f};
      am = MFMA(Wq[(4*8+mt*2+0)*64+lane], B0, am);
      am = MFMA(Wq[(4*8+mt*2+1)*64+lane], B1, am);
      *(float4*)(A_src + (base+c)*64 + mt*16 + 4*g) =
        make_float4(am[0],am[1],am[2],am[3]);
    }
  } else {
    int nb = gridDim.x - nxf;
    int i = (blockIdx.x-nxf)*256 + threadIdx.x, st = nb*256;
    for (; i<E; i+=st) atomicAdd(&cnt[dst[i]], 1);
  }
}

__global__ __launch_bounds__(1024) void scan_k(const int* __restrict__ cnt,
                                               int* __restrict__ row, int Nn){
  __shared__ int part[1024];
  int t = threadIdx.x;
  int C = (Nn + 1023) >> 10;
  int lo = t*C;
  int hi = lo + C; if (hi > Nn) hi = Nn;
  int s = 0;
  for (int i=lo; i<hi; i++) s += cnt[i];
  part[t] = s;
  __syncthreads();
  for (int off=1; off<1024; off<<=1){
    int v = part[t];
    int u = (t>=off) ? part[t-off] : 0;
    __syncthreads();
    part[t] = v + u;
    __syncthreads();
  }
  int excl = (t==0) ? 0 : part[t-1];
  for (int i=lo; i<hi; i++){ row[i] = excl; excl += cnt[i]; }
  if (t==1023) row[Nn] = excl;
}

// ---- fused: blocks [0,NFILL) CSR fill; blocks [NFILL,+) phaseA.
// phaseA: eid-major; gathers are 16B bf16 FRAGMENTS of e_src16/e_dst16
// (4 lanes cover one 64B line per row) injected into the accumulator via
// identity-A MFMA. ef streams; m16 written packed.
#define NFILL 1024
__global__ __launch_bounds__(256) void fillA_k(
    const int* __restrict__ src, const int* __restrict__ dst,
    const int* __restrict__ rowp, int* __restrict__ cnt2,
    int2* __restrict__ pairs, int E,
    const float* __restrict__ ef,
    const __bf16* __restrict__ es16, const __bf16* __restrict__ ed16,
    const float* __restrict__ b_sg, const float* __restrict__ b_dg,
    const float* __restrict__ b_eg,
    const bf16x8* __restrict__ Wq,
    __bf16* __restrict__ m16, int ntiles)
{
  __shared__ bf16x8 wl[8*64];     // W_eg^T frags only
  if (blockIdx.x < NFILL){
    int i = blockIdx.x*256 + threadIdx.x, st = NFILL*256;
    for (; i<E; i+=st){
      int d = dst[i];
      int pos = rowp[d] + atomicAdd(&cnt2[d], 1);
      pairs[pos] = make_int2(i, src[i]);
    }
    return;
  }
  {
    int t = threadIdx.x;
    #pragma unroll
    for (int i=0;i<2;i++) wl[i*256+t] = Wq[i*256+t];   // mats[0]=eg frags 0-7
  }
  __syncthreads();
  int lane = threadIdx.x & 63, g = lane>>4, c = lane&15;
  // identity A-fragments: I0[r][k]=d(k==r), I1[r][k]=d(k==16+r)
  bf16x8 I0, I1;
  #pragma unroll
  for (int j=0;j<8;j++){
    I0[j] = (g*8+j == c)      ? (__bf16)1.0f : (__bf16)0.0f;
    I1[j] = (g*8+j == 16 + c) ? (__bf16)1.0f : (__bf16)0.0f;
  }
  int gw = (blockIdx.x-NFILL)*4 + (threadIdx.x>>6);
  int nw = (gridDim.x-NFILL)*4;
  float bias2[4][4];
  #pragma unroll
  for (int mt=0;mt<4;mt++)
    #pragma unroll
    for (int e=0;e<4;e++){
      int f = mt*16 + 4*g + e;
      bias2[mt][e] = b_sg[f] + b_dg[f] + b_eg[f];
    }
  if (gw >= ntiles) return;
  int sc = src[(long)gw*16 + c], dc = dst[(long)gw*16 + c];
  for (int tt=gw; tt<ntiles; tt+=nw){
    long base = (long)tt*16;
    int tn = tt + nw;
    int sn = sc, dn = dc;
    if (tn < ntiles){ sn = src[(long)tn*16 + c]; dn = dst[(long)tn*16 + c]; }
    // streaming ef fragments (f32 -> bf16)
    const float* rpe = ef + (base+c)*64 + g*8;
    float4 e0=*(const float4*)rpe,      e1=*(const float4*)(rpe+4);
    float4 e2=*(const float4*)(rpe+32), e3=*(const float4*)(rpe+36);
    // gathered bf16 operand fragments: 16B per lane, 64B contiguous per row
    bf16x8 BS0 = *(const bf16x8*)(es16 + (long)sc*64 + g*8);
    bf16x8 BS1 = *(const bf16x8*)(es16 + (long)sc*64 + 32 + g*8);
    bf16x8 BD0 = *(const bf16x8*)(ed16 + (long)dc*64 + g*8);
    bf16x8 BD1 = *(const bf16x8*)(ed16 + (long)dc*64 + 32 + g*8);
    bf16x8 BE0=cvt8(e0,e1), BE1=cvt8(e2,e3);
    #pragma unroll
    for (int mt=0;mt<4;mt++){
      bf16x8 Is = (mt&1) ? I1 : I0;
      f32x4 am = {0.f,0.f,0.f,0.f};
      am = MFMA(wl[(mt*2+0)*64+lane], BE0, am);
      am = MFMA(wl[(mt*2+1)*64+lane], BE1, am);
      am = MFMA(Is, (mt>>1) ? BS1 : BS0, am);
      am = MFMA(Is, (mt>>1) ? BD1 : BD0, am);
      union { __bf16 h[4]; uint2 u; } pk;
      #pragma unroll
      for (int e=0;e<4;e++) pk.h[e] = (__bf16)(am[e] + bias2[mt][e]);
      *(uint2*)(m16 + (base+c)*64 + mt*16 + 4*g) = pk.u;
    }
    sc = sn; dc = dn;
  }
}

// ---- phaseB: node-major over CSR rows; 8-edge unroll. Gathers m16 rows
// (128B) + Bh16 rows (128B); adds b_du / b_su downstream.
__global__ __launch_bounds__(256) void phaseB(
    const __bf16* __restrict__ m16, const int2* __restrict__ pairs,
    const __bf16* __restrict__ bh16, const int* __restrict__ rowp,
    const float* __restrict__ b_du, const float* __restrict__ b_su,
    float* __restrict__ A_src,
    float* __restrict__ est, float* __restrict__ nst, int Nn)
{
  __shared__ float sst[256];
  sst[threadIdx.x] = 0.f;
  __syncthreads();
  int lane = threadIdx.x & 63, w = threadIdx.x>>6;
  float bdu = b_du[lane], bsu = b_su[lane];
  int chunk = (Nn + gridDim.x - 1)/gridDim.x;
  int n0 = blockIdx.x*chunk;
  int n1 = n0 + chunk; if (n1 > Nn) n1 = Nn;
  float e1=0.f, e2=0.f, p1=0.f, p2=0.f;
  for (int n=n0+w; n<n1; n+=4){
    int r0 = rowp[n], r1 = rowp[n+1];
    float ssum=0.f, bsum=0.f;
    int r = r0;
    for (; r+8 <= r1; r+=8){
      int2 q[8];
      #pragma unroll
      for (int j=0;j<8;j++) q[j] = pairs[r+j];
      float mv[8], bh[8];
      #pragma unroll
      for (int j=0;j<8;j++) mv[j] = (float)m16[(long)q[j].x*64 + lane];
      #pragma unroll
      for (int j=0;j<8;j++) bh[j] = (float)bh16[(long)q[j].y*64 + lane] + bdu;
      #pragma unroll
      for (int j=0;j<8;j++){
        float sg = 1.f/(1.f+__expf(-mv[j]));
        ssum += sg; bsum += bh[j]*sg;
        e1 += mv[j]; e2 += mv[j]*mv[j];
      }
    }
    for (; r < r1; ++r){
      int2 q0 = pairs[r];
      float mv0 = (float)m16[(long)q0.x*64 + lane];
      float bh0 = (float)bh16[(long)q0.y*64 + lane] + bdu;
      float sg0 = 1.f/(1.f+__expf(-mv0));
      ssum += sg0; bsum += bh0*sg0;
      e1 += mv0;   e2 += mv0*mv0;
    }
    long xi = (long)n*64 + lane;
    float xp = A_src[xi] + bsu + bsum/(ssum+1e-6f);
    A_src[xi] = xp;
    p1 += xp; p2 += xp*xp;
  }
  atomicAdd(&sst[lane],     e1);
  atomicAdd(&sst[64+lane],  e2);
  atomicAdd(&sst[128+lane], p1);
  atomicAdd(&sst[192+lane], p2);
  __syncthreads();
  int t = threadIdx.x;
  if (t < 128) atomicAdd(&est[t], sst[t]);
  else         atomicAdd(&nst[t-128], sst[t]);
}

// ---- fused finals: blocks [0,NNF) x-output; blocks [NNF,+) y-output.
#define NNF 1024
__global__ __launch_bounds__(256) void finals_k(
    const float* __restrict__ nf, const float* __restrict__ xpre,
    const float* __restrict__ nst, const float* __restrict__ gn,
    const float* __restrict__ btn, float* __restrict__ xo, int Nn,
    const __bf16* __restrict__ m16, const float* __restrict__ ef,
    const float* __restrict__ est, const float* __restrict__ ge,
    const float* __restrict__ bte, float* __restrict__ y, float invE, long E)
{
  if (blockIdx.x < NNF){
    long tid = (long)blockIdx.x*256 + threadIdx.x;
    long stride = (long)NNF*256;
    int col = (int)(tid & 63);
    float invN = 1.f/(float)Nn;
    float mu = nst[col]*invN;
    float var = nst[64+col]*invN - mu*mu;
    float rs = rsqrtf(var + 1e-5f);
    float aa = gn[col]*rs;
    float bb = btn[col] - mu*aa;
    long total = (long)Nn*64;
    for (long i=tid; i<total; i+=stride){
      float z = xpre[i]*aa + bb;
      xo[i] = nf[i] + z/(1.f+__expf(-z));
    }
  } else {
    int oct = threadIdx.x & 7;
    float aa[8], bb[8];
    #pragma unroll
    for (int j=0;j<8;j++){
      int col = oct*8 + j;
      float mu = est[col]*invE;
      float var = est[64+col]*invE - mu*mu;
      float rs = rsqrtf(var + 1e-5f);
      float ga = ge[col]*rs;
      aa[j] = ga; bb[j] = bte[col] - mu*ga;
    }
    long tid = (long)(blockIdx.x-NNF)*256 + threadIdx.x;
    long pstep = ((long)(gridDim.x-NNF)*256) >> 3;
    for (long p = tid>>3; p < E; p += pstep){
      bf16x8 mv = *(const bf16x8*)&m16[p*64 + oct*8];
      const float* rp = ef + p*64 + oct*8;
      float4 f0 = *(const float4*)rp, f1 = *(const float4*)(rp+4);
      float o[8];
      #pragma unroll
      for (int j=0;j<8;j++){
        float z = aa[j]*(float)mv[j] + bb[j];
        float ev = (j<4) ? ((const float*)&f0)[j] : ((const float*)&f1)[j-4];
        o[j] = ev + z/(1.f+__expf(-z));
      }
      float* yp = y + p*64 + oct*8;
      *(float4*)yp     = make_float4(o[0],o[1],o[2],o[3]);
      *(float4*)(yp+4) = make_float4(o[4],o[5],o[6],o[7]);
    }
  }
}

extern "C" void kernel_launch(void* const* d_in, const int* in_sizes, int n_in,
                              void* d_out, int out_size, void* d_ws, size_t ws_size,
                              hipStream_t stream){
  const float* nf  = (const float*)d_in[0];
  const float* ef  = (const float*)d_in[1];
  const int*   src = (const int*)d_in[2];
  const int*   dst = (const int*)d_in[3];
  const float* W_sg=(const float*)d_in[4];  const float* b_sg=(const float*)d_in[5];
  const float* W_dg=(const float*)d_in[6];  const float* b_dg=(const float*)d_in[7];
  const float* W_eg=(const float*)d_in[8];  const float* b_eg=(const float*)d_in[9];
  const float* W_su=(const float*)d_in[10]; const float* b_su=(const float*)d_in[11];
  const float* W_du=(const float*)d_in[12]; const float* b_du=(const float*)d_in[13];
  const float* gn=(const float*)d_in[14];   const float* btn=(const float*)d_in[15];
  const float* ge=(const float*)d_in[16];   const float* bte=(const float*)d_in[17];

  int Nn = in_sizes[0]/64;
  int Ee = in_sizes[2];
  size_t Nf = (size_t)Nn*64;
  size_t Es = (size_t)Ee;

  float* ws    = (float*)d_ws;
  float* A_src = ws;                          // Nf f32 (becomes x_pre)
  __bf16* es16 = (__bf16*)(ws + Nf);          // Nf/2 floats
  __bf16* ed16 = (__bf16*)(ws + Nf + Nf/2);   // Nf/2
  __bf16* bh16 = (__bf16*)(ws + 2*Nf);        // Nf/2
  __bf16* m16  = (__bf16*)(ws + 2*Nf + Nf/2); // 32*Es floats
  int2*  pairs = (int2*)(ws + 2*Nf + Nf/2 + 32*Es);  // 2*Es
  int*   cnt   = (int*)(pairs + Es);          // Nn
  int*   cnt2  = cnt + Nn;                    // Nn
  float* est   = (float*)(cnt2 + Nn);         // 128
  float* nst   = est + 128;                   // 128
  int*   rowp  = (int*)(nst + 128);           // Nn+1
  size_t woff  = 2*Nf + Nf/2 + 32*Es + 2*Es + 2*(size_t)Nn + 256 + (size_t)Nn + 1;
  woff = (woff + 15) & ~(size_t)15;
  bf16x8* Wq   = (bf16x8*)(ws + woff);        // 2560 frags

  float* xo = (float*)d_out;
  float* yo = xo + Nf;

  int nz4 = (int)((2*(size_t)Nn + 256) >> 2);
  setup_k<<<272,256,0,stream>>>(W_sg,W_dg,W_eg,W_su,W_du,Wq,(int4*)cnt,nz4);

  int ntn = Nn/16;
  int nxf = (ntn+3)/4;
  xform_hist_k<<<nxf+2048,256,0,stream>>>(nf,Wq,es16,ed16,bh16,A_src,ntn,nxf,
                                          dst,cnt,Ee);
  scan_k<<<1,1024,0,stream>>>(cnt,rowp,Nn);
  int nte = Ee/16;
  fillA_k<<<NFILL+4096,256,0,stream>>>(src,dst,rowp,cnt2,pairs,Ee,
                                       ef,es16,ed16,b_sg,b_dg,b_eg,Wq,m16,nte);
  phaseB<<<4096,256,0,stream>>>(m16,pairs,bh16,rowp,b_du,b_su,A_src,est,nst,Nn);
  finals_k<<<NNF+4096,256,0,stream>>>(nf,A_src,nst,gn,btn,xo,Nn,
                                      m16,ef,est,ge,bte,yo,
                                      1.f/(float)Ee,(long)Ee);
}

// Round 15
// 864.160 us; speedup vs baseline: 1.0799x; 1.0443x over previous
//
#include <hip/hip_runtime.h>
#include <hip/hip_bf16.h>

typedef __attribute__((ext_vector_type(8))) __bf16 bf16x8;
typedef __attribute__((ext_vector_type(4))) float f32x4;

#define MFMA(a,b,c) __builtin_amdgcn_mfma_f32_16x16x32_bf16((a),(b),(c),0,0,0)

__device__ __forceinline__ bf16x8 cvt8(float4 a, float4 b){
  bf16x8 r;
  r[0]=(__bf16)a.x; r[1]=(__bf16)a.y; r[2]=(__bf16)a.z; r[3]=(__bf16)a.w;
  r[4]=(__bf16)b.x; r[5]=(__bf16)b.y; r[6]=(__bf16)b.z; r[7]=(__bf16)b.w;
  return r;
}

// ---- fused setup: blocks 0-15 pack weights into transposed A-operand layout,
// blocks 16+ zero the counter/stat region.
// Wq mats {0:eg,1:sg,2:dg,3:du,4:su}; frag=mt*2+kh; lane(c,g) holds
// W[kh*32+g*8+j][mt*16+c]  — 2560 frags.
__global__ void setup_k(const float* __restrict__ W_sg, const float* __restrict__ W_dg,
                        const float* __restrict__ W_eg, const float* __restrict__ W_su,
                        const float* __restrict__ W_du,
                        bf16x8* __restrict__ Wq,
                        int4* __restrict__ zp, int nz4){
  if (blockIdx.x < 16){
    int tid = blockIdx.x*256 + threadIdx.x;
    if (tid >= 2560) return;
    int lane = tid & 63, g = lane>>4, c = lane&15;
    int frag = (tid>>6)&7, m = tid>>9;
    const float* Ws[5] = {W_eg, W_sg, W_dg, W_du, W_su};
    const float* W = Ws[m];
    int mt = frag>>1, kh = frag&1;
    bf16x8 v;
    #pragma unroll
    for (int j=0;j<8;j++) v[j] = (__bf16)W[(kh*32+g*8+j)*64 + mt*16 + c];
    Wq[tid] = v;
  } else {
    int i = (blockIdx.x-16)*256 + threadIdx.x, st = (gridDim.x-16)*256;
    for (; i<nz4; i+=st) zp[i] = make_int4(0,0,0,0);
  }
}

// ---- fused: blocks [0,nxf): 4 node transforms via transposed MFMA ->
// e_src16/e_dst16/Bh16 (bf16 rows, NO bias) + A_src (f32, NO bias);
// blocks [nxf,+): dst histogram.
__global__ __launch_bounds__(256) void xform_hist_k(
    const float* __restrict__ nf, const bf16x8* __restrict__ Wq,
    __bf16* __restrict__ es16, __bf16* __restrict__ ed16,
    __bf16* __restrict__ bh16, float* __restrict__ A_src, int ntiles, int nxf,
    const int* __restrict__ dst, int* __restrict__ cnt, int E)
{
  if ((int)blockIdx.x < nxf){
    int lane = threadIdx.x & 63;
    int gw = blockIdx.x*4 + (threadIdx.x>>6);
    if (gw >= ntiles) return;
    int g = lane>>4, c = lane&15;
    long base = (long)gw*16;
    const float* rp = nf + (base + c)*64 + g*8;
    float4 a0 = *(const float4*)rp,      a1 = *(const float4*)(rp+4);
    float4 a2 = *(const float4*)(rp+32), a3 = *(const float4*)(rp+36);
    bf16x8 B0 = cvt8(a0,a1), B1 = cvt8(a2,a3);
    __bf16* outs[3] = {es16, ed16, bh16};
    const int mats[3] = {1,2,3};           // sg, dg, du
    #pragma unroll
    for (int i=0;i<3;i++){
      #pragma unroll
      for (int mt=0;mt<4;mt++){
        f32x4 am = {0.f,0.f,0.f,0.f};
        am = MFMA(Wq[(mats[i]*8+mt*2+0)*64+lane], B0, am);
        am = MFMA(Wq[(mats[i]*8+mt*2+1)*64+lane], B1, am);
        union { __bf16 h[4]; uint2 u; } pk;
        #pragma unroll
        for (int e=0;e<4;e++) pk.h[e] = (__bf16)am[e];
        *(uint2*)(outs[i] + (base+c)*64 + mt*16 + 4*g) = pk.u;
      }
    }
    #pragma unroll
    for (int mt=0;mt<4;mt++){
      f32x4 am = {0.f,0.f,0.f,0.f};
      am = MFMA(Wq[(4*8+mt*2+0)*64+lane], B0, am);
      am = MFMA(Wq[(4*8+mt*2+1)*64+lane], B1, am);
      *(float4*)(A_src + (base+c)*64 + mt*16 + 4*g) =
        make_float4(am[0],am[1],am[2],am[3]);
    }
  } else {
    int nb = gridDim.x - nxf;
    int i = (blockIdx.x-nxf)*256 + threadIdx.x, st = nb*256;
    for (; i<E; i+=st) atomicAdd(&cnt[dst[i]], 1);
  }
}

__global__ __launch_bounds__(1024) void scan_k(const int* __restrict__ cnt,
                                               int* __restrict__ row, int Nn){
  __shared__ int part[1024];
  int t = threadIdx.x;
  int C = (Nn + 1023) >> 10;
  int lo = t*C;
  int hi = lo + C; if (hi > Nn) hi = Nn;
  int s = 0;
  for (int i=lo; i<hi; i++) s += cnt[i];
  part[t] = s;
  __syncthreads();
  for (int off=1; off<1024; off<<=1){
    int v = part[t];
    int u = (t>=off) ? part[t-off] : 0;
    __syncthreads();
    part[t] = v + u;
    __syncthreads();
  }
  int excl = (t==0) ? 0 : part[t-1];
  for (int i=lo; i<hi; i++){ row[i] = excl; excl += cnt[i]; }
  if (t==1023) row[Nn] = excl;
}

// slim per-tile payload: 4 streaming ef frags + 4 gathered bf16 operand frags
struct T2 {
  float4 e0,e1,e2,e3;
  bf16x8 bs0,bs1,bd0,bd1;
};

__device__ __forceinline__ T2 ld_t2(const float* __restrict__ ef,
                                    const __bf16* __restrict__ es16,
                                    const __bf16* __restrict__ ed16,
                                    long base, int c, int g, int sc, int dc){
  T2 t;
  const float* rpe = ef + (base+c)*64 + g*8;
  t.e0=*(const float4*)rpe;      t.e1=*(const float4*)(rpe+4);
  t.e2=*(const float4*)(rpe+32); t.e3=*(const float4*)(rpe+36);
  t.bs0 = *(const bf16x8*)(es16 + (long)sc*64 + g*8);
  t.bs1 = *(const bf16x8*)(es16 + (long)sc*64 + 32 + g*8);
  t.bd0 = *(const bf16x8*)(ed16 + (long)dc*64 + g*8);
  t.bd1 = *(const bf16x8*)(ed16 + (long)dc*64 + 32 + g*8);
  return t;
}

// ---- fused: blocks [0,NFILL) CSR fill; blocks [NFILL,+) phaseA.
// phaseA: eid-major; 2-deep register pipeline (tile t+1's 8 loads in flight
// during tile t's compute); m16 stores staged through XOR-swizzled LDS and
// written as 2 fully-coalesced 1KB store instructions per tile.
#define NFILL 1024
__global__ __launch_bounds__(256) void fillA_k(
    const int* __restrict__ src, const int* __restrict__ dst,
    const int* __restrict__ rowp, int* __restrict__ cnt2,
    int2* __restrict__ pairs, int E,
    const float* __restrict__ ef,
    const __bf16* __restrict__ es16, const __bf16* __restrict__ ed16,
    const float* __restrict__ b_sg, const float* __restrict__ b_dg,
    const float* __restrict__ b_eg,
    const bf16x8* __restrict__ Wq,
    __bf16* __restrict__ m16, int ntiles)
{
  __shared__ bf16x8 wl[8*64];      // W_eg^T frags (8KB)
  __shared__ uint2 mst[4][256];    // per-wave m16 tile stage (8KB)
  if (blockIdx.x < NFILL){
    int i = blockIdx.x*256 + threadIdx.x, st = NFILL*256;
    for (; i<E; i+=st){
      int d = dst[i];
      int pos = rowp[d] + atomicAdd(&cnt2[d], 1);
      pairs[pos] = make_int2(i, src[i]);
    }
    return;
  }
  {
    int t = threadIdx.x;
    #pragma unroll
    for (int i=0;i<2;i++) wl[i*256+t] = Wq[i*256+t];   // eg frags 0-7
  }
  __syncthreads();
  int lane = threadIdx.x & 63, g = lane>>4, c = lane&15;
  int wv = threadIdx.x>>6;
  // identity A-fragments: I0[r][k]=d(k==r), I1[r][k]=d(k==16+r)
  bf16x8 I0, I1;
  #pragma unroll
  for (int j=0;j<8;j++){
    I0[j] = (g*8+j == c)      ? (__bf16)1.0f : (__bf16)0.0f;
    I1[j] = (g*8+j == 16 + c) ? (__bf16)1.0f : (__bf16)0.0f;
  }
  int gw = (blockIdx.x-NFILL)*4 + wv;
  int nw = (gridDim.x-NFILL)*4;
  float bias2[4][4];
  #pragma unroll
  for (int mt=0;mt<4;mt++)
    #pragma unroll
    for (int e=0;e<4;e++){
      int f = mt*16 + 4*g + e;
      bias2[mt][e] = b_sg[f] + b_dg[f] + b_eg[f];
    }
  if (gw >= ntiles) return;
  // prologue: idx(t0), data(t0), idx(t1)
  int sc = src[(long)gw*16 + c], dc = dst[(long)gw*16 + c];
  T2 cur = ld_t2(ef, es16, ed16, (long)gw*16, c, g, sc, dc);
  int t1i = gw + nw;
  int sn = sc, dn = dc;
  if (t1i < ntiles){ sn = src[(long)t1i*16 + c]; dn = dst[(long)t1i*16 + c]; }
  // output-copy lane mapping (coalesced store of the staged 2KB tile)
  int r_o = lane>>3;              // 0..7 (+k*8)
  int u0_o = (lane&7)*2;
  for (int tt=gw; tt<ntiles; tt+=nw){
    int t1 = tt + nw;
    // issue next tile's 8 data loads (held in regs; compiler emits counted waits)
    T2 nxt;
    if (t1 < ntiles) nxt = ld_t2(ef, es16, ed16, (long)t1*16, c, g, sn, dn);
    // prefetch indices 2 ahead
    int t2 = t1 + nw;
    if (t2 < ntiles){ sn = src[(long)t2*16 + c]; dn = dst[(long)t2*16 + c]; }
    // compute current tile into LDS stage
    bf16x8 BE0=cvt8(cur.e0,cur.e1), BE1=cvt8(cur.e2,cur.e3);
    #pragma unroll
    for (int mt=0;mt<4;mt++){
      bf16x8 Is = (mt&1) ? I1 : I0;
      f32x4 am = {0.f,0.f,0.f,0.f};
      am = MFMA(wl[(mt*2+0)*64+lane], BE0, am);
      am = MFMA(wl[(mt*2+1)*64+lane], BE1, am);
      am = MFMA(Is, (mt>>1) ? cur.bs1 : cur.bs0, am);
      am = MFMA(Is, (mt>>1) ? cur.bd1 : cur.bd0, am);
      union { __bf16 h[4]; uint2 u; } pk;
      #pragma unroll
      for (int e=0;e<4;e++) pk.h[e] = (__bf16)(am[e] + bias2[mt][e]);
      int u = mt*4 + g;                        // 8B unit within row c
      mst[wv][c*16 + (u^c)] = pk.u;            // XOR-swizzled (bank-spread)
    }
    // write out 2KB tile as 2 coalesced 1KB store instructions
    char* tb = (char*)m16 + (size_t)tt*16*128;
    #pragma unroll
    for (int k=0;k<2;k++){
      int r = k*8 + r_o;
      uint2 a = mst[wv][r*16 + ( u0_o      ^ r)];
      uint2 b = mst[wv][r*16 + ((u0_o + 1) ^ r)];
      *(uint4*)(tb + k*1024 + lane*16) = make_uint4(a.x,a.y,b.x,b.y);
    }
    cur = nxt;
  }
}

// ---- phaseB: node-major over CSR rows; 8-edge unroll. Gathers m16 rows
// (128B) + Bh16 rows (128B); adds b_du / b_su downstream.
__global__ __launch_bounds__(256) void phaseB(
    const __bf16* __restrict__ m16, const int2* __restrict__ pairs,
    const __bf16* __restrict__ bh16, const int* __restrict__ rowp,
    const float* __restrict__ b_du, const float* __restrict__ b_su,
    float* __restrict__ A_src,
    float* __restrict__ est, float* __restrict__ nst, int Nn)
{
  __shared__ float sst[256];
  sst[threadIdx.x] = 0.f;
  __syncthreads();
  int lane = threadIdx.x & 63, w = threadIdx.x>>6;
  float bdu = b_du[lane], bsu = b_su[lane];
  int chunk = (Nn + gridDim.x - 1)/gridDim.x;
  int n0 = blockIdx.x*chunk;
  int n1 = n0 + chunk; if (n1 > Nn) n1 = Nn;
  float e1=0.f, e2=0.f, p1=0.f, p2=0.f;
  for (int n=n0+w; n<n1; n+=4){
    int r0 = rowp[n], r1 = rowp[n+1];
    float ssum=0.f, bsum=0.f;
    int r = r0;
    for (; r+8 <= r1; r+=8){
      int2 q[8];
      #pragma unroll
      for (int j=0;j<8;j++) q[j] = pairs[r+j];
      float mv[8], bh[8];
      #pragma unroll
      for (int j=0;j<8;j++) mv[j] = (float)m16[(long)q[j].x*64 + lane];
      #pragma unroll
      for (int j=0;j<8;j++) bh[j] = (float)bh16[(long)q[j].y*64 + lane] + bdu;
      #pragma unroll
      for (int j=0;j<8;j++){
        float sg = 1.f/(1.f+__expf(-mv[j]));
        ssum += sg; bsum += bh[j]*sg;
        e1 += mv[j]; e2 += mv[j]*mv[j];
      }
    }
    for (; r < r1; ++r){
      int2 q0 = pairs[r];
      float mv0 = (float)m16[(long)q0.x*64 + lane];
      float bh0 = (float)bh16[(long)q0.y*64 + lane] + bdu;
      float sg0 = 1.f/(1.f+__expf(-mv0));
      ssum += sg0; bsum += bh0*sg0;
      e1 += mv0;   e2 += mv0*mv0;
    }
    long xi = (long)n*64 + lane;
    float xp = A_src[xi] + bsu + bsum/(ssum+1e-6f);
    A_src[xi] = xp;
    p1 += xp; p2 += xp*xp;
  }
  atomicAdd(&sst[lane],     e1);
  atomicAdd(&sst[64+lane],  e2);
  atomicAdd(&sst[128+lane], p1);
  atomicAdd(&sst[192+lane], p2);
  __syncthreads();
  int t = threadIdx.x;
  if (t < 128) atomicAdd(&est[t], sst[t]);
  else         atomicAdd(&nst[t-128], sst[t]);
}

// ---- fused finals: blocks [0,NNF) x-output; blocks [NNF,+) y-output.
#define NNF 1024
__global__ __launch_bounds__(256) void finals_k(
    const float* __restrict__ nf, const float* __restrict__ xpre,
    const float* __restrict__ nst, const float* __restrict__ gn,
    const float* __restrict__ btn, float* __restrict__ xo, int Nn,
    const __bf16* __restrict__ m16, const float* __restrict__ ef,
    const float* __restrict__ est, const float* __restrict__ ge,
    const float* __restrict__ bte, float* __restrict__ y, float invE, long E)
{
  if (blockIdx.x < NNF){
    long tid = (long)blockIdx.x*256 + threadIdx.x;
    long stride = (long)NNF*256;
    int col = (int)(tid & 63);
    float invN = 1.f/(float)Nn;
    float mu = nst[col]*invN;
    float var = nst[64+col]*invN - mu*mu;
    float rs = rsqrtf(var + 1e-5f);
    float aa = gn[col]*rs;
    float bb = btn[col] - mu*aa;
    long total = (long)Nn*64;
    for (long i=tid; i<total; i+=stride){
      float z = xpre[i]*aa + bb;
      xo[i] = nf[i] + z/(1.f+__expf(-z));
    }
  } else {
    int oct = threadIdx.x & 7;
    float aa[8], bb[8];
    #pragma unroll
    for (int j=0;j<8;j++){
      int col = oct*8 + j;
      float mu = est[col]*invE;
      float var = est[64+col]*invE - mu*mu;
      float rs = rsqrtf(var + 1e-5f);
      float ga = ge[col]*rs;
      aa[j] = ga; bb[j] = bte[col] - mu*ga;
    }
    long tid = (long)(blockIdx.x-NNF)*256 + threadIdx.x;
    long pstep = ((long)(gridDim.x-NNF)*256) >> 3;
    for (long p = tid>>3; p < E; p += pstep){
      bf16x8 mv = *(const bf16x8*)&m16[p*64 + oct*8];
      const float* rp = ef + p*64 + oct*8;
      float4 f0 = *(const float4*)rp, f1 = *(const float4*)(rp+4);
      float o[8];
      #pragma unroll
      for (int j=0;j<8;j++){
        float z = aa[j]*(float)mv[j] + bb[j];
        float ev = (j<4) ? ((const float*)&f0)[j] : ((const float*)&f1)[j-4];
        o[j] = ev + z/(1.f+__expf(-z));
      }
      float* yp = y + p*64 + oct*8;
      *(float4*)yp     = make_float4(o[0],o[1],o[2],o[3]);
      *(float4*)(yp+4) = make_float4(o[4],o[5],o[6],o[7]);
    }
  }
}

extern "C" void kernel_launch(void* const* d_in, const int* in_sizes, int n_in,
                              void* d_out, int out_size, void* d_ws, size_t ws_size,
                              hipStream_t stream){
  const float* nf  = (const float*)d_in[0];
  const float* ef  = (const float*)d_in[1];
  const int*   src = (const int*)d_in[2];
  const int*   dst = (const int*)d_in[3];
  const float* W_sg=(const float*)d_in[4];  const float* b_sg=(const float*)d_in[5];
  const float* W_dg=(const float*)d_in[6];  const float* b_dg=(const float*)d_in[7];
  const float* W_eg=(const float*)d_in[8];  const float* b_eg=(const float*)d_in[9];
  const float* W_su=(const float*)d_in[10]; const float* b_su=(const float*)d_in[11];
  const float* W_du=(const float*)d_in[12]; const float* b_du=(const float*)d_in[13];
  const float* gn=(const float*)d_in[14];   const float* btn=(const float*)d_in[15];
  const float* ge=(const float*)d_in[16];   const float* bte=(const float*)d_in[17];

  int Nn = in_sizes[0]/64;
  int Ee = in_sizes[2];
  size_t Nf = (size_t)Nn*64;
  size_t Es = (size_t)Ee;

  float* ws    = (float*)d_ws;
  float* A_src = ws;                          // Nf f32 (becomes x_pre)
  __bf16* es16 = (__bf16*)(ws + Nf);          // Nf/2 floats
  __bf16* ed16 = (__bf16*)(ws + Nf + Nf/2);   // Nf/2
  __bf16* bh16 = (__bf16*)(ws + 2*Nf);        // Nf/2
  __bf16* m16  = (__bf16*)(ws + 2*Nf + Nf/2); // 32*Es floats
  int2*  pairs = (int2*)(ws + 2*Nf + Nf/2 + 32*Es);  // 2*Es
  int*   cnt   = (int*)(pairs + Es);          // Nn
  int*   cnt2  = cnt + Nn;                    // Nn
  float* est   = (float*)(cnt2 + Nn);         // 128
  float* nst   = est + 128;                   // 128
  int*   rowp  = (int*)(nst + 128);           // Nn+1
  size_t woff  = 2*Nf + Nf/2 + 32*Es + 2*Es + 2*(size_t)Nn + 256 + (size_t)Nn + 1;
  woff = (woff + 15) & ~(size_t)15;
  bf16x8* Wq   = (bf16x8*)(ws + woff);        // 2560 frags

  float* xo = (float*)d_out;
  float* yo = xo + Nf;

  int nz4 = (int)((2*(size_t)Nn + 256) >> 2);
  setup_k<<<272,256,0,stream>>>(W_sg,W_dg,W_eg,W_su,W_du,Wq,(int4*)cnt,nz4);

  int ntn = Nn/16;
  int nxf = (ntn+3)/4;
  xform_hist_k<<<nxf+2048,256,0,stream>>>(nf,Wq,es16,ed16,bh16,A_src,ntn,nxf,
                                          dst,cnt,Ee);
  scan_k<<<1,1024,0,stream>>>(cnt,rowp,Nn);
  int nte = Ee/16;
  fillA_k<<<NFILL+4096,256,0,stream>>>(src,dst,rowp,cnt2,pairs,Ee,
                                       ef,es16,ed16,b_sg,b_dg,b_eg,Wq,m16,nte);
  phaseB<<<4096,256,0,stream>>>(m16,pairs,bh16,rowp,b_du,b_su,A_src,est,nst,Nn);
  finals_k<<<NNF+4096,256,0,stream>>>(nf,A_src,nst,gn,btn,xo,Nn,
                                      m16,ef,est,ge,bte,yo,
                                      1.f/(float)Ee,(long)Ee);
}